// Round 14
// baseline (105.875 us; speedup 1.0000x reference)
//
#include <hip/hip_runtime.h>
#include <hip/hip_bf16.h>

// Problem constants (match reference)
constexpr int F_ = 16;        // N_FEATURES
constexpr int K_ = 8;         // NUM_INSTANCES
constexpr int B_ = 16;        // batch
constexpr int HW_ = 512 * 512;
constexpr float DELTA_V = 0.5f;
constexpr float TWO_DELTA_D = 3.0f;   // 2 * 1.5
constexpr float GAMMA = 0.001f;

constexpr int CHUNKS = 64;            // chunks per image
constexpr int PIX = HW_ / CHUNKS;     // 4096 pixels per chunk
constexpr int SLOT = 136;             // per-block partial: 128 sums + 8 counts
constexpr int NPART = B_ * CHUNKS;    // 1024 blocks

// workspace layout (in floats)
constexpr int OFF_PART  = 0;                          // NPART*SLOT
constexpr int OFF_IMG   = OFF_PART + NPART * SLOT;    // B*2 (ldist, lreg per image)
constexpr int OFF_LVARP = OFF_IMG + 2 * B_;           // NPART per-block lvar partials
constexpr int OFF_DONE  = OFF_LVARP + NPART;          // 1 u32 (zeroed by k1 via RMW)
constexpr int OFF_LAB8  = OFF_DONE + 16;              // B*HW bytes (uint8 labels, from k1)

__device__ inline float waveReduceSum(float v) {
#pragma unroll
  for (int off = 32; off > 0; off >>= 1)
    v += __shfl_down(v, off, 64);
  return v;
}

__device__ inline float comp(const float4& v, int i) {
  return i == 0 ? v.x : i == 1 ? v.y : i == 2 ? v.z : v.w;
}

// PUBLISH via relaxed atomic RMW: executes at the coherence point, immediately
// visible to other XCDs; relaxed -> no cache-maintenance cost. (R13-proven.)
__device__ inline void dpublish(float* p, float v) {
  __hip_atomic_exchange(p, v, __ATOMIC_RELAXED, __HIP_MEMORY_SCOPE_AGENT);
}
// READ via +0.0 RMW: forces the read to execute at the coherence point.
__device__ inline float dread_rmw(float* p) {
  return __hip_atomic_fetch_add(p, 0.0f, __ATOMIC_RELAXED, __HIP_MEMORY_SCOPE_AGENT);
}

// Pass 1: per-(image,chunk) partial counts + feature sums -> ws slots (no atomics).
// Also side-publishes labels as uint8 (pass 2 then reads 4 MB instead of 16 MB).
// grid (CHUNKS, B), block (64, 4): wave wy owns features [4*wy, 4*wy+4)
__global__ __launch_bounds__(256) void k1_sums(const float* __restrict__ pred,
                                               const int* __restrict__ tgt,
                                               float* __restrict__ ws) {
  float* part = ws + OFF_PART;
  unsigned char* lab8 = (unsigned char*)(ws + OFF_LAB8);
  const int b = blockIdx.y;
  const int chunk = blockIdx.x;
  const int lane = threadIdx.x;   // 0..63
  const int wy = threadIdx.y;     // 0..3

  if (b == 0 && chunk == 0 && lane == 0 && wy == 0) {
    unsigned* done = (unsigned*)(ws + OFF_DONE);
    __hip_atomic_exchange(done, 0u, __ATOMIC_RELAXED, __HIP_MEMORY_SCOPE_AGENT);
  }

  float acc[4][8];
#pragma unroll
  for (int j = 0; j < 4; ++j)
#pragma unroll
    for (int k = 0; k < 8; ++k) acc[j][k] = 0.f;
  float cnt[8];
#pragma unroll
  for (int k = 0; k < 8; ++k) cnt[k] = 0.f;

  const int* tb = tgt + b * HW_ + chunk * PIX;
  const float* pb = pred + (size_t)b * F_ * HW_ + chunk * PIX;
  unsigned char* lb8 = lab8 + b * HW_ + chunk * PIX;

  constexpr int ITERS = PIX / 256;  // 16 (64 lanes x 4 pixels per iter)
#pragma unroll 1
  for (int it = 0; it < ITERS; ++it) {
    const int p = it * 256 + lane * 4;
    const int4 lb = *reinterpret_cast<const int4*>(tb + p);
    float4 xr[4];
#pragma unroll
    for (int j = 0; j < 4; ++j)
      xr[j] = *reinterpret_cast<const float4*>(pb + (wy * 4 + j) * HW_ + p);

    const int labs[4] = {lb.x, lb.y, lb.z, lb.w};
    if (wy == 0) {  // one wave publishes the uint8 labels (coalesced uchar4)
      uchar4 pk;
      pk.x = (unsigned char)lb.x;
      pk.y = (unsigned char)lb.y;
      pk.z = (unsigned char)lb.z;
      pk.w = (unsigned char)lb.w;
      *reinterpret_cast<uchar4*>(lb8 + p) = pk;
    }
    float sel[4][8];
#pragma unroll
    for (int pp = 0; pp < 4; ++pp)
#pragma unroll
      for (int k = 0; k < 8; ++k) sel[pp][k] = (labs[pp] == k) ? 1.f : 0.f;

#pragma unroll
    for (int j = 0; j < 4; ++j) {
#pragma unroll
      for (int k = 0; k < 8; ++k) {
        acc[j][k] = fmaf(sel[0][k], xr[j].x, acc[j][k]);
        acc[j][k] = fmaf(sel[1][k], xr[j].y, acc[j][k]);
        acc[j][k] = fmaf(sel[2][k], xr[j].z, acc[j][k]);
        acc[j][k] = fmaf(sel[3][k], xr[j].w, acc[j][k]);
      }
    }
    if (wy == 0) {
#pragma unroll
      for (int k = 0; k < 8; ++k)
        cnt[k] += sel[0][k] + sel[1][k] + sel[2][k] + sel[3][k];
    }
  }

  float* slot = part + (size_t)(b * CHUNKS + chunk) * SLOT;
#pragma unroll
  for (int j = 0; j < 4; ++j)
#pragma unroll
    for (int k = 0; k < 8; ++k) {
      float v = waveReduceSum(acc[j][k]);
      if (lane == 0) slot[k * F_ + wy * 4 + j] = v;
    }
  if (wy == 0) {
#pragma unroll
    for (int k = 0; k < 8; ++k) {
      float v = waveReduceSum(cnt[k]);
      if (lane == 0) slot[128 + k] = v;
    }
  }
}

// Pass 2: per-block mu prologue + l_var + done-tail finalize.
// grid (CHUNKS, B), block 256. Labels read from the uint8 side copy.
__global__ __launch_bounds__(256) void k3_lvar(const float* __restrict__ pred,
                                               float* __restrict__ ws,
                                               float* __restrict__ out) {
  const float* part = ws + OFF_PART;
  float* img   = ws + OFF_IMG;
  float* lvarp = ws + OFF_LVARP;
  unsigned* done = (unsigned*)(ws + OFF_DONE);
  const unsigned char* lab8 = (const unsigned char*)(ws + OFF_LAB8);
  const int b = blockIdx.y, chunk = blockIdx.x;
  const int t = threadIdx.x;
  const int bid = b * CHUNKS + chunk;

  __shared__ float tot[SLOT];
  __shared__ alignas(16) float mu_s[8][20];  // 80B rows: 16B aligned, banks spread
  __shared__ float inv_s[8];
  __shared__ float red[4];
  __shared__ int islast;

  // ---- Prologue: reduce this image's 64 partial slots -> mu, inv (L2-served,
  //      coalesced: at fixed c the 136 threads read contiguous 544B) ----
  if (t < SLOT) {
    float s = 0.f;
    const float* p = part + (size_t)b * CHUNKS * SLOT + t;
#pragma unroll 8
    for (int c = 0; c < CHUNKS; ++c) s += p[(size_t)c * SLOT];
    tot[t] = s;
  }
  __syncthreads();
  if (t < 8) inv_s[t] = 1.f / fmaxf(tot[128 + t], 1.f);
  __syncthreads();
  if (t < 128) mu_s[t >> 4][t & 15] = tot[t] * inv_s[t >> 4];
  __syncthreads();

  // ---- Only the chunk-0 block computes l_dist + l_reg for this image ----
  if (chunk == 0) {
    __shared__ float lreg_arr[8];
    if (t < 8) {
      float s = 0.f;
#pragma unroll
      for (int f = 0; f < 16; ++f) s = fmaf(mu_s[t][f], mu_s[t][f], s);
      lreg_arr[t] = sqrtf(s);
    }
    if (t < 64) {
      int a = t >> 3, c2 = t & 7;
      float v = 0.f;
      if (a != c2) {
        float dsq = 0.f;
#pragma unroll
        for (int f = 0; f < 16; ++f) {
          float dd = mu_s[a][f] - mu_s[c2][f];
          dsq = fmaf(dd, dd, dsq);
        }
        float h = fmaxf(TWO_DELTA_D - sqrtf(dsq), 0.f);
        v = h * h;
      }
      v = waveReduceSum(v);
      if (t == 0) dpublish(&img[b * 2 + 0], v);
    }
    __syncthreads();
    if (t == 0) {
      float lr = 0.f;
#pragma unroll
      for (int k = 0; k < 8; ++k) lr += lreg_arr[k];
      dpublish(&img[b * 2 + 1], lr);
    }
  }

  // ---- Main: l_var over this chunk (reversed; 16 loads hoisted; u8 labels) ----
  const unsigned char* lb8 = lab8 + b * HW_ + chunk * PIX;
  const float* pb = pred + (size_t)b * F_ * HW_ + chunk * PIX;

  float lsum = 0.f;
  constexpr int ITERS = PIX / 1024;  // 4 (256 threads x 4 pixels)
#pragma unroll 1
  for (int it = ITERS - 1; it >= 0; --it) {
    const int p = it * 1024 + t * 4;
    const uchar4 lb = *reinterpret_cast<const uchar4*>(lb8 + p);
    float4 xr[16];
#pragma unroll
    for (int f = 0; f < 16; ++f)
      xr[f] = *reinterpret_cast<const float4*>(pb + f * HW_ + p);

    const int labs[4] = {(int)lb.x, (int)lb.y, (int)lb.z, (int)lb.w};
    float d2[4] = {0.f, 0.f, 0.f, 0.f};
#pragma unroll
    for (int pp = 0; pp < 4; ++pp) {
      const float* mrow = &mu_s[labs[pp]][0];
#pragma unroll
      for (int f4 = 0; f4 < 4; ++f4) {
        const float4 m = *reinterpret_cast<const float4*>(mrow + f4 * 4);
        float e0 = comp(xr[f4 * 4 + 0], pp) - m.x;
        float e1 = comp(xr[f4 * 4 + 1], pp) - m.y;
        float e2 = comp(xr[f4 * 4 + 2], pp) - m.z;
        float e3 = comp(xr[f4 * 4 + 3], pp) - m.w;
        float s = fmaf(e0, e0, 0.f);
        s = fmaf(e1, e1, s);
        s = fmaf(e2, e2, s);
        s = fmaf(e3, e3, s);
        d2[pp] += s;
      }
    }
#pragma unroll
    for (int pp = 0; pp < 4; ++pp) {
      float dist = sqrtf(d2[pp]);
      float h = fmaxf(dist - DELTA_V, 0.f);
      lsum = fmaf(h * h, inv_s[labs[pp]], lsum);
    }
  }
  float v = waveReduceSum(lsum);
  const int lane = t & 63, wid = t >> 6;
  if (lane == 0) red[wid] = v;
  __syncthreads();

  // ---- Tail: publish partial (RMW), drain, count arrival (counter zeroed by k1) ----
  if (t == 0) {
    dpublish(&lvarp[bid], red[0] + red[1] + red[2] + red[3]);
    asm volatile("s_waitcnt vmcnt(0)" ::: "memory");
    unsigned d = __hip_atomic_fetch_add(done, 1u, __ATOMIC_RELAXED,
                                        __HIP_MEMORY_SCOPE_AGENT);
    islast = (d == (unsigned)(NPART - 1));
  }
  __syncthreads();

  if (islast) {
    __shared__ float red2[4];
    __shared__ float ldlr[32];
    float s = 0.f;
#pragma unroll
    for (int j = 0; j < 4; ++j) s += dread_rmw(&lvarp[t * 4 + j]);
    float vv = waveReduceSum(s);
    if (lane == 0) red2[wid] = vv;
    if (t < 32) ldlr[t] = dread_rmw(&img[t]);
    __syncthreads();
    if (t == 0) {
      float lv = red2[0] + red2[1] + red2[2] + red2[3];
      float ld = 0.f, lr = 0.f;
#pragma unroll
      for (int bb = 0; bb < B_; ++bb) {
        ld += ldlr[bb * 2 + 0];
        lr += ldlr[bb * 2 + 1];
      }
      lv *= 1.f / (K_ * (float)B_);
      ld *= 1.f / (K_ * (K_ - 1) * (float)B_);
      lr *= 1.f / (K_ * (float)B_);
      out[0] = lv + ld + GAMMA * lr;
      out[1] = lv;
      out[2] = ld;
      out[3] = lr;
    }
  }
}

extern "C" void kernel_launch(void* const* d_in, const int* in_sizes, int n_in,
                              void* d_out, int out_size, void* d_ws, size_t ws_size,
                              hipStream_t stream) {
  const float* pred = (const float*)d_in[0];
  const int* tgt = (const int*)d_in[1];
  float* out = (float*)d_out;
  float* ws = (float*)d_ws;

  hipLaunchKernelGGL(k1_sums, dim3(CHUNKS, B_), dim3(64, 4), 0, stream, pred, tgt, ws);
  hipLaunchKernelGGL(k3_lvar, dim3(CHUNKS, B_), dim3(256), 0, stream, pred, ws, out);
}

// Round 15
// 103.919 us; speedup vs baseline: 1.0188x; 1.0188x over previous
//
#include <hip/hip_runtime.h>
#include <hip/hip_bf16.h>

// Problem constants (match reference)
constexpr int F_ = 16;        // N_FEATURES
constexpr int K_ = 8;         // NUM_INSTANCES
constexpr int B_ = 16;        // batch
constexpr int HW_ = 512 * 512;
constexpr float DELTA_V = 0.5f;
constexpr float TWO_DELTA_D = 3.0f;   // 2 * 1.5
constexpr float GAMMA = 0.001f;

constexpr int CHUNKS = 64;            // chunks per image
constexpr int PIX = HW_ / CHUNKS;     // 4096 pixels per chunk
constexpr int SLOT = 136;             // per-block partial: 128 sums + 8 counts
constexpr int NPART = B_ * CHUNKS;    // 1024 blocks

// workspace layout (in floats) — no region needs zero-init (all plain stores)
constexpr int OFF_PART  = 0;                          // NPART*SLOT
constexpr int OFF_IMG   = OFF_PART + NPART * SLOT;    // B*2 (ldist, lreg per image)
constexpr int OFF_LVARP = OFF_IMG + 2 * B_;           // NPART per-block lvar partials

__device__ inline float waveReduceSum(float v) {
#pragma unroll
  for (int off = 32; off > 0; off >>= 1)
    v += __shfl_down(v, off, 64);
  return v;
}

__device__ inline float comp(const float4& v, int i) {
  return i == 0 ? v.x : i == 1 ? v.y : i == 2 ? v.z : v.w;
}

// Pass 1: per-(image,chunk) partial counts + feature sums -> ws slots (no atomics).
// grid (CHUNKS, B), block (64, 4): wave wy owns features [4*wy, 4*wy+4)
__global__ __launch_bounds__(256) void k1_sums(const float* __restrict__ pred,
                                               const int* __restrict__ tgt,
                                               float* __restrict__ ws) {
  float* part = ws + OFF_PART;
  const int b = blockIdx.y;
  const int chunk = blockIdx.x;
  const int lane = threadIdx.x;   // 0..63
  const int wy = threadIdx.y;     // 0..3

  float acc[4][8];
#pragma unroll
  for (int j = 0; j < 4; ++j)
#pragma unroll
    for (int k = 0; k < 8; ++k) acc[j][k] = 0.f;
  float cnt[8];
#pragma unroll
  for (int k = 0; k < 8; ++k) cnt[k] = 0.f;

  const int* tb = tgt + b * HW_ + chunk * PIX;
  const float* pb = pred + (size_t)b * F_ * HW_ + chunk * PIX;

  constexpr int ITERS = PIX / 256;  // 16 (64 lanes x 4 pixels per iter)
#pragma unroll 1
  for (int it = 0; it < ITERS; ++it) {
    const int p = it * 256 + lane * 4;
    const int4 lb = *reinterpret_cast<const int4*>(tb + p);
    float4 xr[4];
#pragma unroll
    for (int j = 0; j < 4; ++j)
      xr[j] = *reinterpret_cast<const float4*>(pb + (wy * 4 + j) * HW_ + p);

    const int labs[4] = {lb.x, lb.y, lb.z, lb.w};
    float sel[4][8];
#pragma unroll
    for (int pp = 0; pp < 4; ++pp)
#pragma unroll
      for (int k = 0; k < 8; ++k) sel[pp][k] = (labs[pp] == k) ? 1.f : 0.f;

#pragma unroll
    for (int j = 0; j < 4; ++j) {
#pragma unroll
      for (int k = 0; k < 8; ++k) {
        acc[j][k] = fmaf(sel[0][k], xr[j].x, acc[j][k]);
        acc[j][k] = fmaf(sel[1][k], xr[j].y, acc[j][k]);
        acc[j][k] = fmaf(sel[2][k], xr[j].z, acc[j][k]);
        acc[j][k] = fmaf(sel[3][k], xr[j].w, acc[j][k]);
      }
    }
    if (wy == 0) {
#pragma unroll
      for (int k = 0; k < 8; ++k)
        cnt[k] += sel[0][k] + sel[1][k] + sel[2][k] + sel[3][k];
    }
  }

  float* slot = part + (size_t)(b * CHUNKS + chunk) * SLOT;
#pragma unroll
  for (int j = 0; j < 4; ++j)
#pragma unroll
    for (int k = 0; k < 8; ++k) {
      float v = waveReduceSum(acc[j][k]);
      if (lane == 0) slot[k * F_ + wy * 4 + j] = v;
    }
  if (wy == 0) {
#pragma unroll
    for (int k = 0; k < 8; ++k) {
      float v = waveReduceSum(cnt[k]);
      if (lane == 0) slot[128 + k] = v;
    }
  }
}

// Pass 2: per-block mu prologue (redundant, no sync) + l_var main loop.
// grid (CHUNKS, B), block 256. chunk-0 block also writes l_dist/l_reg for its image.
// Per-block lvar partial written to a distinct slot (no atomics anywhere).
__global__ __launch_bounds__(256) void k3_lvar(const float* __restrict__ pred,
                                               const int* __restrict__ tgt,
                                               float* __restrict__ ws) {
  const float* part = ws + OFF_PART;
  float* img   = ws + OFF_IMG;
  float* lvarp = ws + OFF_LVARP;
  const int b = blockIdx.y, chunk = blockIdx.x;
  const int t = threadIdx.x;

  __shared__ float tot[SLOT];
  __shared__ alignas(16) float mu_s[8][20];  // 80B rows: 16B aligned, banks spread
  __shared__ float inv_s[8];
  __shared__ float red[4];

  // ---- Prologue: reduce this image's 64 partial slots -> mu, inv (L2-served) ----
  if (t < SLOT) {
    float s = 0.f;
    const float* p = part + (size_t)b * CHUNKS * SLOT + t;
#pragma unroll 8
    for (int c = 0; c < CHUNKS; ++c) s += p[(size_t)c * SLOT];
    tot[t] = s;
  }
  __syncthreads();
  if (t < 8) inv_s[t] = 1.f / fmaxf(tot[128 + t], 1.f);
  __syncthreads();
  if (t < 128) mu_s[t >> 4][t & 15] = tot[t] * inv_s[t >> 4];
  __syncthreads();

  // ---- Only the chunk-0 block computes l_dist + l_reg for this image ----
  if (chunk == 0) {
    __shared__ float lreg_arr[8];
    if (t < 8) {
      float s = 0.f;
#pragma unroll
      for (int f = 0; f < 16; ++f) s = fmaf(mu_s[t][f], mu_s[t][f], s);
      lreg_arr[t] = sqrtf(s);
    }
    if (t < 64) {
      int a = t >> 3, c2 = t & 7;
      float v = 0.f;
      if (a != c2) {
        float dsq = 0.f;
#pragma unroll
        for (int f = 0; f < 16; ++f) {
          float dd = mu_s[a][f] - mu_s[c2][f];
          dsq = fmaf(dd, dd, dsq);
        }
        float h = fmaxf(TWO_DELTA_D - sqrtf(dsq), 0.f);
        v = h * h;
      }
      v = waveReduceSum(v);
      if (t == 0) img[b * 2 + 0] = v;
    }
    __syncthreads();
    if (t == 0) {
      float lr = 0.f;
#pragma unroll
      for (int k = 0; k < 8; ++k) lr += lreg_arr[k];
      img[b * 2 + 1] = lr;
    }
  }

  // ---- Main: l_var over this chunk (reversed; 16 loads hoisted) ----
  const int* tb = tgt + b * HW_ + chunk * PIX;
  const float* pb = pred + (size_t)b * F_ * HW_ + chunk * PIX;

  float lsum = 0.f;
  constexpr int ITERS = PIX / 1024;  // 4 (256 threads x 4 pixels)
#pragma unroll 1
  for (int it = ITERS - 1; it >= 0; --it) {
    const int p = it * 1024 + t * 4;
    const int4 lb = *reinterpret_cast<const int4*>(tb + p);
    float4 xr[16];
#pragma unroll
    for (int f = 0; f < 16; ++f)
      xr[f] = *reinterpret_cast<const float4*>(pb + f * HW_ + p);

    const int labs[4] = {lb.x, lb.y, lb.z, lb.w};
    float d2[4] = {0.f, 0.f, 0.f, 0.f};
#pragma unroll
    for (int pp = 0; pp < 4; ++pp) {
      const float* mrow = &mu_s[labs[pp]][0];
#pragma unroll
      for (int f4 = 0; f4 < 4; ++f4) {
        const float4 m = *reinterpret_cast<const float4*>(mrow + f4 * 4);
        float e0 = comp(xr[f4 * 4 + 0], pp) - m.x;
        float e1 = comp(xr[f4 * 4 + 1], pp) - m.y;
        float e2 = comp(xr[f4 * 4 + 2], pp) - m.z;
        float e3 = comp(xr[f4 * 4 + 3], pp) - m.w;
        float s = fmaf(e0, e0, 0.f);
        s = fmaf(e1, e1, s);
        s = fmaf(e2, e2, s);
        s = fmaf(e3, e3, s);
        d2[pp] += s;
      }
    }
#pragma unroll
    for (int pp = 0; pp < 4; ++pp) {
      float dist = sqrtf(d2[pp]);
      float h = fmaxf(dist - DELTA_V, 0.f);
      lsum = fmaf(h * h, inv_s[labs[pp]], lsum);
    }
  }
  float v = waveReduceSum(lsum);
  const int lane = t & 63, wid = t >> 6;
  if (lane == 0) red[wid] = v;
  __syncthreads();
  if (t == 0) lvarp[b * CHUNKS + chunk] = red[0] + red[1] + red[2] + red[3];
}

// Final: sum 1024 lvar partials + 16 (ldist,lreg) pairs -> out[4]. 1 block x 256.
__global__ __launch_bounds__(256) void k4_final(const float* __restrict__ ws,
                                                float* __restrict__ out) {
  const float* img = ws + OFF_IMG;
  const float* lvarp = ws + OFF_LVARP;
  const int t = threadIdx.x;
  __shared__ float red[4];
  __shared__ float ldlr[32];

  float s = 0.f;
#pragma unroll
  for (int j = 0; j < 4; ++j) s += lvarp[t * 4 + j];
  float v = waveReduceSum(s);
  const int lane = t & 63, wid = t >> 6;
  if (lane == 0) red[wid] = v;
  if (t < 32) ldlr[t] = img[t];
  __syncthreads();
  if (t == 0) {
    float lv = red[0] + red[1] + red[2] + red[3];
    float ld = 0.f, lr = 0.f;
#pragma unroll
    for (int bb = 0; bb < B_; ++bb) {
      ld += ldlr[bb * 2 + 0];
      lr += ldlr[bb * 2 + 1];
    }
    lv *= 1.f / (K_ * (float)B_);
    ld *= 1.f / (K_ * (K_ - 1) * (float)B_);
    lr *= 1.f / (K_ * (float)B_);
    out[0] = lv + ld + GAMMA * lr;
    out[1] = lv;
    out[2] = ld;
    out[3] = lr;
  }
}

extern "C" void kernel_launch(void* const* d_in, const int* in_sizes, int n_in,
                              void* d_out, int out_size, void* d_ws, size_t ws_size,
                              hipStream_t stream) {
  const float* pred = (const float*)d_in[0];
  const int* tgt = (const int*)d_in[1];
  float* out = (float*)d_out;
  float* ws = (float*)d_ws;

  hipLaunchKernelGGL(k1_sums, dim3(CHUNKS, B_), dim3(64, 4), 0, stream, pred, tgt, ws);
  hipLaunchKernelGGL(k3_lvar, dim3(CHUNKS, B_), dim3(256), 0, stream, pred, tgt, ws);
  hipLaunchKernelGGL(k4_final, dim3(1), dim3(256), 0, stream, ws, out);
}